// Round 2
// baseline (137.494 us; speedup 1.0000x reference)
//
#include <hip/hip_runtime.h>
#include <hip/hip_bf16.h>

// Shapes (fixed by the problem)
#define NMOVES 4096
#define LW     15
#define DIM    1024
#define VOC    32
#define NROW   480   // VOC * LW distinct (token, position) rows
#define XROW   48    // [letter(32); pos(15); bias(1)] factored rows
#define G48LD  64    // G48 leading dim (full 64x64 MFMA tile)

typedef __attribute__((ext_vector_type(8))) short  short8;   // 8 bf16 (4 VGPRs)
typedef __attribute__((ext_vector_type(4))) float  floatx4;  // MFMA C/D

__device__ __forceinline__ unsigned short f2b(float f) {
  unsigned int x;
  __builtin_memcpy(&x, &f, 4);
  x = x + 0x7FFFu + ((x >> 16) & 1u);  // round-to-nearest-even
  return (unsigned short)(x >> 16);
}
__device__ __forceinline__ ushort4 cvt4(float4 v) {
  ushort4 o; o.x = f2b(v.x); o.y = f2b(v.y); o.z = f2b(v.z); o.w = f2b(v.w);
  return o;
}
__device__ __forceinline__ float b2f(unsigned short u) {
  unsigned int x = ((unsigned int)u) << 16;
  float f;
  __builtin_memcpy(&f, &x, 4);
  return f;
}

#define LDK 72   // 64 + 8 bf16 pad: 144 B row stride, 16B-aligned

// ---------------------------------------------------------------------------
// K1: factored projections.  X = [letter(32); pos(15)] (47 rows, padded 64).
// Xq/Xk/Xv[47,1024] = X · W^T   (fp32 out, NO bias — bias handled downstream)
// Grid (1,16,3): 48 blocks, 64x64 tile, 16 K-iters, reg-prefetch dbuf,
// fp32 sources converted to bf16 at LDS-write time.
// ---------------------------------------------------------------------------
__global__ __launch_bounds__(256) void proj_small(
    const float* __restrict__ letter, const float* __restrict__ pos,
    const float* __restrict__ Wq, const float* __restrict__ Wk,
    const float* __restrict__ Wv,
    float* __restrict__ Xq, float* __restrict__ Xk, float* __restrict__ Xv) {
  __shared__ __attribute__((aligned(16))) unsigned short lA[64 * LDK];
  __shared__ __attribute__((aligned(16))) unsigned short lB[64 * LDK];

  const float* W = (blockIdx.z == 0) ? Wq : (blockIdx.z == 1) ? Wk : Wv;
  float*       O = (blockIdx.z == 0) ? Xq : (blockIdx.z == 1) ? Xk : Xv;

  const int bn0 = blockIdx.y * 64;   // col tile

  const int tid  = threadIdx.x;
  const int lane = tid & 63;
  const int wave = tid >> 6;
  const int wr   = wave >> 1;
  const int wc   = wave & 1;
  const int quad = lane >> 4;
  const int l16  = lane & 15;
  const int srow = tid >> 3;          // 32 rows per half
  const int scol = (tid & 7) << 3;    // 8 elems per thread

  // A sources: half0 = letter rows 0..31; half1 = pos rows (srow<15) else zero
  const float* aptr0 = letter + (size_t)srow * DIM + scol;
  const bool   av1   = (srow < LW);
  const float* aptr1 = av1 ? (pos + (size_t)srow * DIM + scol) : letter;
  const float* bptr0 = W + (size_t)(bn0 + srow) * DIM + scol;
  const float* bptr1 = bptr0 + (size_t)32 * DIM;

  const float4 z4 = make_float4(0.f, 0.f, 0.f, 0.f);
  float4 ra00 = *reinterpret_cast<const float4*>(aptr0);
  float4 ra01 = *reinterpret_cast<const float4*>(aptr0 + 4);
  float4 ra10 = av1 ? *reinterpret_cast<const float4*>(aptr1)     : z4;
  float4 ra11 = av1 ? *reinterpret_cast<const float4*>(aptr1 + 4) : z4;
  float4 rb00 = *reinterpret_cast<const float4*>(bptr0);
  float4 rb01 = *reinterpret_cast<const float4*>(bptr0 + 4);
  float4 rb10 = *reinterpret_cast<const float4*>(bptr1);
  float4 rb11 = *reinterpret_cast<const float4*>(bptr1 + 4);

  floatx4 acc[2][2];
#pragma unroll
  for (int i = 0; i < 2; ++i)
#pragma unroll
    for (int j = 0; j < 2; ++j) acc[i][j] = (floatx4){0.f, 0.f, 0.f, 0.f};

  for (int k0 = 0; k0 < DIM; k0 += 64) {
    *reinterpret_cast<ushort4*>(lA + srow * LDK + scol)            = cvt4(ra00);
    *reinterpret_cast<ushort4*>(lA + srow * LDK + scol + 4)        = cvt4(ra01);
    *reinterpret_cast<ushort4*>(lA + (srow + 32) * LDK + scol)     = cvt4(ra10);
    *reinterpret_cast<ushort4*>(lA + (srow + 32) * LDK + scol + 4) = cvt4(ra11);
    *reinterpret_cast<ushort4*>(lB + srow * LDK + scol)            = cvt4(rb00);
    *reinterpret_cast<ushort4*>(lB + srow * LDK + scol + 4)        = cvt4(rb01);
    *reinterpret_cast<ushort4*>(lB + (srow + 32) * LDK + scol)     = cvt4(rb10);
    *reinterpret_cast<ushort4*>(lB + (srow + 32) * LDK + scol + 4) = cvt4(rb11);
    __syncthreads();
    if (k0 + 64 < DIM) {  // prefetch next tile; MFMA hides latency
      const int k = k0 + 64;
      ra00 = *reinterpret_cast<const float4*>(aptr0 + k);
      ra01 = *reinterpret_cast<const float4*>(aptr0 + k + 4);
      ra10 = av1 ? *reinterpret_cast<const float4*>(aptr1 + k)     : z4;
      ra11 = av1 ? *reinterpret_cast<const float4*>(aptr1 + k + 4) : z4;
      rb00 = *reinterpret_cast<const float4*>(bptr0 + k);
      rb01 = *reinterpret_cast<const float4*>(bptr0 + k + 4);
      rb10 = *reinterpret_cast<const float4*>(bptr1 + k);
      rb11 = *reinterpret_cast<const float4*>(bptr1 + k + 4);
    }
#pragma unroll
    for (int kk = 0; kk < 64; kk += 32) {
      short8 a0 = *reinterpret_cast<const short8*>(lA + (wr * 32 + l16) * LDK + kk + quad * 8);
      short8 a1 = *reinterpret_cast<const short8*>(lA + (wr * 32 + 16 + l16) * LDK + kk + quad * 8);
      short8 b0 = *reinterpret_cast<const short8*>(lB + (wc * 32 + l16) * LDK + kk + quad * 8);
      short8 b1 = *reinterpret_cast<const short8*>(lB + (wc * 32 + 16 + l16) * LDK + kk + quad * 8);
      acc[0][0] = __builtin_amdgcn_mfma_f32_16x16x32_bf16(a0, b0, acc[0][0], 0, 0, 0);
      acc[0][1] = __builtin_amdgcn_mfma_f32_16x16x32_bf16(a0, b1, acc[0][1], 0, 0, 0);
      acc[1][0] = __builtin_amdgcn_mfma_f32_16x16x32_bf16(a1, b0, acc[1][0], 0, 0, 0);
      acc[1][1] = __builtin_amdgcn_mfma_f32_16x16x32_bf16(a1, b1, acc[1][1], 0, 0, 0);
    }
    __syncthreads();
  }

#pragma unroll
  for (int mi = 0; mi < 2; ++mi) {
#pragma unroll
    for (int ni = 0; ni < 2; ++ni) {
      const int gcol = bn0 + wc * 32 + ni * 16 + l16;
#pragma unroll
      for (int i = 0; i < 4; ++i) {
        const int grow = wr * 32 + mi * 16 + quad * 4 + i;
        if (grow < XROW - 1)  // rows 0..46
          O[(size_t)grow * DIM + gcol] = acc[mi][ni][i];
      }
    }
  }
}

// ---------------------------------------------------------------------------
// K2: fused gram48 + V-expand (disjoint blocks).
// Block 0:   G48[48,64] = [Xq;bq] · [Xk;bk]^T   (one 64x64 MFMA tile, K=1024)
// Blocks 1+: Vb[r=t*15+l] = bf16(Xv[t] + Xv[32+l] + bv)   (480x1024)
// ---------------------------------------------------------------------------
__global__ __launch_bounds__(256) void gram_vexp(
    const float* __restrict__ Xq, const float* __restrict__ Xk,
    const float* __restrict__ bq, const float* __restrict__ bk,
    const float* __restrict__ Xv, const float* __restrict__ bv,
    float* __restrict__ G48, unsigned short* __restrict__ Vb) {
  const int tid = threadIdx.x;

  if (blockIdx.x == 0) {
    __shared__ __attribute__((aligned(16))) unsigned short lA[64 * LDK];
    __shared__ __attribute__((aligned(16))) unsigned short lB[64 * LDK];

    const int lane = tid & 63;
    const int wave = tid >> 6;
    const int wr   = wave >> 1;
    const int wc   = wave & 1;
    const int quad = lane >> 4;
    const int l16  = lane & 15;
    const int srow = tid >> 3;
    const int scol = (tid & 7) << 3;

    // half0 rows 0..31 <- Xq/Xk; half1: rows 32..46 <- Xq/Xk, row 47 <- bias
    const float* aptr0 = Xq + (size_t)srow * DIM + scol;
    const float* bptr0 = Xk + (size_t)srow * DIM + scol;
    const bool   v1    = (srow <= LW);
    const float* aptr1 = (srow < LW) ? (Xq + (size_t)(32 + srow) * DIM + scol)
                                     : (srow == LW ? (bq + scol) : Xq);
    const float* bptr1 = (srow < LW) ? (Xk + (size_t)(32 + srow) * DIM + scol)
                                     : (srow == LW ? (bk + scol) : Xk);

    const float4 z4 = make_float4(0.f, 0.f, 0.f, 0.f);
    float4 ra00 = *reinterpret_cast<const float4*>(aptr0);
    float4 ra01 = *reinterpret_cast<const float4*>(aptr0 + 4);
    float4 ra10 = v1 ? *reinterpret_cast<const float4*>(aptr1)     : z4;
    float4 ra11 = v1 ? *reinterpret_cast<const float4*>(aptr1 + 4) : z4;
    float4 rb00 = *reinterpret_cast<const float4*>(bptr0);
    float4 rb01 = *reinterpret_cast<const float4*>(bptr0 + 4);
    float4 rb10 = v1 ? *reinterpret_cast<const float4*>(bptr1)     : z4;
    float4 rb11 = v1 ? *reinterpret_cast<const float4*>(bptr1 + 4) : z4;

    floatx4 acc[2][2];
#pragma unroll
    for (int i = 0; i < 2; ++i)
#pragma unroll
      for (int j = 0; j < 2; ++j) acc[i][j] = (floatx4){0.f, 0.f, 0.f, 0.f};

    for (int k0 = 0; k0 < DIM; k0 += 64) {
      *reinterpret_cast<ushort4*>(lA + srow * LDK + scol)            = cvt4(ra00);
      *reinterpret_cast<ushort4*>(lA + srow * LDK + scol + 4)        = cvt4(ra01);
      *reinterpret_cast<ushort4*>(lA + (srow + 32) * LDK + scol)     = cvt4(ra10);
      *reinterpret_cast<ushort4*>(lA + (srow + 32) * LDK + scol + 4) = cvt4(ra11);
      *reinterpret_cast<ushort4*>(lB + srow * LDK + scol)            = cvt4(rb00);
      *reinterpret_cast<ushort4*>(lB + srow * LDK + scol + 4)        = cvt4(rb01);
      *reinterpret_cast<ushort4*>(lB + (srow + 32) * LDK + scol)     = cvt4(rb10);
      *reinterpret_cast<ushort4*>(lB + (srow + 32) * LDK + scol + 4) = cvt4(rb11);
      __syncthreads();
      if (k0 + 64 < DIM) {
        const int k = k0 + 64;
        ra00 = *reinterpret_cast<const float4*>(aptr0 + k);
        ra01 = *reinterpret_cast<const float4*>(aptr0 + k + 4);
        ra10 = v1 ? *reinterpret_cast<const float4*>(aptr1 + k)     : z4;
        ra11 = v1 ? *reinterpret_cast<const float4*>(aptr1 + k + 4) : z4;
        rb00 = *reinterpret_cast<const float4*>(bptr0 + k);
        rb01 = *reinterpret_cast<const float4*>(bptr0 + k + 4);
        rb10 = v1 ? *reinterpret_cast<const float4*>(bptr1 + k)     : z4;
        rb11 = v1 ? *reinterpret_cast<const float4*>(bptr1 + k + 4) : z4;
      }
#pragma unroll
      for (int kk = 0; kk < 64; kk += 32) {
        short8 a0 = *reinterpret_cast<const short8*>(lA + (wr * 32 + l16) * LDK + kk + quad * 8);
        short8 a1 = *reinterpret_cast<const short8*>(lA + (wr * 32 + 16 + l16) * LDK + kk + quad * 8);
        short8 b0 = *reinterpret_cast<const short8*>(lB + (wc * 32 + l16) * LDK + kk + quad * 8);
        short8 b1 = *reinterpret_cast<const short8*>(lB + (wc * 32 + 16 + l16) * LDK + kk + quad * 8);
        acc[0][0] = __builtin_amdgcn_mfma_f32_16x16x32_bf16(a0, b0, acc[0][0], 0, 0, 0);
        acc[0][1] = __builtin_amdgcn_mfma_f32_16x16x32_bf16(a0, b1, acc[0][1], 0, 0, 0);
        acc[1][0] = __builtin_amdgcn_mfma_f32_16x16x32_bf16(a1, b0, acc[1][0], 0, 0, 0);
        acc[1][1] = __builtin_amdgcn_mfma_f32_16x16x32_bf16(a1, b1, acc[1][1], 0, 0, 0);
      }
      __syncthreads();
    }

#pragma unroll
    for (int mi = 0; mi < 2; ++mi) {
#pragma unroll
      for (int ni = 0; ni < 2; ++ni) {
        const int gcol = wc * 32 + ni * 16 + l16;
#pragma unroll
        for (int i = 0; i < 4; ++i) {
          const int grow = wr * 32 + mi * 16 + quad * 4 + i;
          if (grow < XROW)
            G48[(size_t)grow * G48LD + gcol] = acc[mi][ni][i];
        }
      }
    }
  } else {
    // V-expand: 240 blocks x 256 thr x 8 elems = 480*1024
    const int c   = (blockIdx.x - 1) * 256 + tid;
    const int row = c >> 7;             // 128 chunks per row
    const int col = (c & 127) << 3;
    const int t   = row / LW;
    const int l   = row - t * LW;
    const float* lv = Xv + (size_t)t * DIM + col;
    const float* pv = Xv + (size_t)(32 + l) * DIM + col;
    const float* bb = bv + col;
    float4 x0 = *reinterpret_cast<const float4*>(lv);
    float4 x1 = *reinterpret_cast<const float4*>(lv + 4);
    float4 p0 = *reinterpret_cast<const float4*>(pv);
    float4 p1 = *reinterpret_cast<const float4*>(pv + 4);
    float4 b0 = *reinterpret_cast<const float4*>(bb);
    float4 b1 = *reinterpret_cast<const float4*>(bb + 4);
    ushort4 o0, o1;
    o0.x = f2b(x0.x + p0.x + b0.x); o0.y = f2b(x0.y + p0.y + b0.y);
    o0.z = f2b(x0.z + p0.z + b0.z); o0.w = f2b(x0.w + p0.w + b0.w);
    o1.x = f2b(x1.x + p1.x + b1.x); o1.y = f2b(x1.y + p1.y + b1.y);
    o1.z = f2b(x1.z + p1.z + b1.z); o1.w = f2b(x1.w + p1.w + b1.w);
    *reinterpret_cast<ushort4*>(Vb + (size_t)row * DIM + col)     = o0;
    *reinterpret_cast<ushort4*>(Vb + (size_t)row * DIM + col + 4) = o1;
  }
}

// ---------------------------------------------------------------------------
// K3: per-move attention via the 48x48 table. One block per move.
// S[l][j] = sum over {t_l,32+l} x {t_j,32+j} + bias-row terms (row-constant
// terms dropped — softmax-invariant). P = softmax_j(S); w_j = 2*sum_l P[l][j];
// out[m] = sum_j w_j * Vb[r_j]   (bf16 V, fp32 out)
// ---------------------------------------------------------------------------
__global__ __launch_bounds__(256) void attn_out_k(
    const void* __restrict__ tokens_raw, const float* __restrict__ G48,
    const unsigned short* __restrict__ Vb, float* __restrict__ out) {
  __shared__ __attribute__((aligned(16))) float Gs[XROW * G48LD];  // 12 KB
  __shared__ int   tok[LW];
  __shared__ int   ridx[LW];
  __shared__ float S[LW][16];
  __shared__ float w[16];
  __shared__ int   is64_s;
  const int m = blockIdx.x;
  const int tid = threadIdx.x;

  const unsigned int* u32 = (const unsigned int*)tokens_raw;
  if (tid < 64) {  // int64 tokens (<32) have all odd 32-bit words zero
    unsigned int v = u32[2 * tid + 1];
    unsigned long long nz = __ballot(v != 0);
    if (tid == 0) is64_s = (nz == 0ULL) ? 1 : 0;
  }
  __syncthreads();

  if (tid < LW) {
    int t;
    if (is64_s) t = (int)((const long long*)tokens_raw)[m * LW + tid];
    else        t = ((const int*)tokens_raw)[m * LW + tid];
    tok[tid]  = t;
    ridx[tid] = t * LW + tid;
  }
#pragma unroll
  for (int i = 0; i < 3; ++i) {  // 768 float4 = 48x64 floats
    const int idx = i * 256 + tid;
    reinterpret_cast<float4*>(Gs)[idx] =
        reinterpret_cast<const float4*>(G48)[idx];
  }
  __syncthreads();

  if (tid < LW * LW) {
    const int l = tid / LW;
    const int j = tid - l * LW;
    const int a0 = tok[l], a1 = 32 + l;
    const int b0 = tok[j], b1 = 32 + j;
    S[l][j] = Gs[a0 * G48LD + b0] + Gs[a0 * G48LD + b1] +
              Gs[a1 * G48LD + b0] + Gs[a1 * G48LD + b1] +
              Gs[(XROW - 1) * G48LD + b0] + Gs[(XROW - 1) * G48LD + b1];
  }
  __syncthreads();

  if (tid < LW) {  // row softmax (over j)
    float mx = -1e30f;
#pragma unroll
    for (int j = 0; j < LW; ++j) mx = fmaxf(mx, S[tid][j]);
    float s = 0.f;
#pragma unroll
    for (int j = 0; j < LW; ++j) { float e = __expf(S[tid][j] - mx); S[tid][j] = e; s += e; }
    const float inv = 1.0f / s;
#pragma unroll
    for (int j = 0; j < LW; ++j) S[tid][j] *= inv;
  }
  __syncthreads();

  if (tid < LW) {  // column weights, with the 2x folded in
    float s = 0.f;
#pragma unroll
    for (int l = 0; l < LW; ++l) s += S[l][tid];
    w[tid] = 2.0f * s;
  }
  __syncthreads();

  const int e0 = tid * 4;  // 256 threads x 4 = 1024 outputs
  float a0 = 0.f, a1 = 0.f, a2 = 0.f, a3 = 0.f;
#pragma unroll
  for (int j = 0; j < LW; ++j) {
    const float wj = w[j];
    ushort4 vv = *reinterpret_cast<const ushort4*>(Vb + (size_t)ridx[j] * DIM + e0);
    a0 += wj * b2f(vv.x);
    a1 += wj * b2f(vv.y);
    a2 += wj * b2f(vv.z);
    a3 += wj * b2f(vv.w);
  }
  *reinterpret_cast<float4*>(out + (size_t)m * DIM + e0) =
      make_float4(a0, a1, a2, a3);
}

// ---------------------------------------------------------------------------
extern "C" void kernel_launch(void* const* d_in, const int* in_sizes, int n_in,
                              void* d_out, int out_size, void* d_ws, size_t ws_size,
                              hipStream_t stream) {
  const void*  tokens = d_in[0];
  const float* letter = (const float*)d_in[1];
  const float* pos    = (const float*)d_in[2];
  const float* Wq     = (const float*)d_in[3];
  const float* bq     = (const float*)d_in[4];
  const float* Wk     = (const float*)d_in[5];
  const float* bk     = (const float*)d_in[6];
  const float* Wv     = (const float*)d_in[7];
  const float* bv     = (const float*)d_in[8];
  float*       outp   = (float*)d_out;   // reference output dtype = float32

  char* ws = (char*)d_ws;
  const size_t XSZ  = (size_t)XROW * DIM * 4;     // 192 KB each (row 47 unused)
  const size_t GSZ  = (size_t)G48LD * G48LD * 4;  // 16 KB
  float* Xq = (float*)(ws);
  float* Xk = (float*)(ws + XSZ);
  float* Xv = (float*)(ws + 2 * XSZ);
  float* Gp = (float*)(ws + 3 * XSZ);
  unsigned short* Vb = (unsigned short*)(ws + 3 * XSZ + GSZ);  // 1 MB

  proj_small<<<dim3(1, 16, 3), 256, 0, stream>>>(letter, pos, Wq, Wk, Wv,
                                                 Xq, Xk, Xv);
  gram_vexp<<<1 + (NROW * DIM / 8 / 256), 256, 0, stream>>>(Xq, Xk, bq, bk,
                                                            Xv, bv, Gp, Vb);
  attn_out_k<<<NMOVES, 256, 0, stream>>>(tokens, Gp, Vb, outp);
}

// Round 3
// 136.743 us; speedup vs baseline: 1.0055x; 1.0055x over previous
//
#include <hip/hip_runtime.h>
#include <hip/hip_bf16.h>

// Shapes (fixed by the problem)
#define NMOVES 4096
#define LW     15
#define DIM    1024
#define VOC    32
#define NROW   480   // VOC * LW distinct (token, position) rows
#define XROW   48    // [letter(32); pos(15); bias(1)] factored rows
#define G48LD  64    // G48 leading dim

typedef __attribute__((ext_vector_type(8))) short  short8;   // 8 bf16 (4 VGPRs)
typedef __attribute__((ext_vector_type(4))) float  floatx4;  // MFMA C/D

__device__ __forceinline__ unsigned short f2b(float f) {
  unsigned int x;
  __builtin_memcpy(&x, &f, 4);
  x = x + 0x7FFFu + ((x >> 16) & 1u);  // round-to-nearest-even
  return (unsigned short)(x >> 16);
}
__device__ __forceinline__ ushort4 cvt4(float4 v) {
  ushort4 o; o.x = f2b(v.x); o.y = f2b(v.y); o.z = f2b(v.z); o.w = f2b(v.w);
  return o;
}
__device__ __forceinline__ float b2f(unsigned short u) {
  unsigned int x = ((unsigned int)u) << 16;
  float f;
  __builtin_memcpy(&f, &x, 4);
  return f;
}

#define LDK 72   // 64 + 8 bf16 pad: 144 B row stride, 16B-aligned

// ---------------------------------------------------------------------------
// K1: factored projections.  X = [letter(32); pos(15)] (47 rows, padded 64).
// Xq/Xk/Xv[47,1024] = X · W^T   (fp32 out, NO bias — bias handled downstream)
// Grid (1,16,3): 48 blocks, 64x64 tile, 16 K-iters, reg-prefetch dbuf.
// ---------------------------------------------------------------------------
__global__ __launch_bounds__(256) void proj_small(
    const float* __restrict__ letter, const float* __restrict__ pos,
    const float* __restrict__ Wq, const float* __restrict__ Wk,
    const float* __restrict__ Wv,
    float* __restrict__ Xq, float* __restrict__ Xk, float* __restrict__ Xv) {
  __shared__ __attribute__((aligned(16))) unsigned short lA[64 * LDK];
  __shared__ __attribute__((aligned(16))) unsigned short lB[64 * LDK];

  const float* W = (blockIdx.z == 0) ? Wq : (blockIdx.z == 1) ? Wk : Wv;
  float*       O = (blockIdx.z == 0) ? Xq : (blockIdx.z == 1) ? Xk : Xv;

  const int bn0 = blockIdx.y * 64;   // col tile

  const int tid  = threadIdx.x;
  const int lane = tid & 63;
  const int wave = tid >> 6;
  const int wr   = wave >> 1;
  const int wc   = wave & 1;
  const int quad = lane >> 4;
  const int l16  = lane & 15;
  const int srow = tid >> 3;          // 32 rows per half
  const int scol = (tid & 7) << 3;    // 8 elems per thread

  const float* aptr0 = letter + (size_t)srow * DIM + scol;
  const bool   av1   = (srow < LW);
  const float* aptr1 = av1 ? (pos + (size_t)srow * DIM + scol) : letter;
  const float* bptr0 = W + (size_t)(bn0 + srow) * DIM + scol;
  const float* bptr1 = bptr0 + (size_t)32 * DIM;

  const float4 z4 = make_float4(0.f, 0.f, 0.f, 0.f);
  float4 ra00 = *reinterpret_cast<const float4*>(aptr0);
  float4 ra01 = *reinterpret_cast<const float4*>(aptr0 + 4);
  float4 ra10 = av1 ? *reinterpret_cast<const float4*>(aptr1)     : z4;
  float4 ra11 = av1 ? *reinterpret_cast<const float4*>(aptr1 + 4) : z4;
  float4 rb00 = *reinterpret_cast<const float4*>(bptr0);
  float4 rb01 = *reinterpret_cast<const float4*>(bptr0 + 4);
  float4 rb10 = *reinterpret_cast<const float4*>(bptr1);
  float4 rb11 = *reinterpret_cast<const float4*>(bptr1 + 4);

  floatx4 acc[2][2];
#pragma unroll
  for (int i = 0; i < 2; ++i)
#pragma unroll
    for (int j = 0; j < 2; ++j) acc[i][j] = (floatx4){0.f, 0.f, 0.f, 0.f};

  for (int k0 = 0; k0 < DIM; k0 += 64) {
    *reinterpret_cast<ushort4*>(lA + srow * LDK + scol)            = cvt4(ra00);
    *reinterpret_cast<ushort4*>(lA + srow * LDK + scol + 4)        = cvt4(ra01);
    *reinterpret_cast<ushort4*>(lA + (srow + 32) * LDK + scol)     = cvt4(ra10);
    *reinterpret_cast<ushort4*>(lA + (srow + 32) * LDK + scol + 4) = cvt4(ra11);
    *reinterpret_cast<ushort4*>(lB + srow * LDK + scol)            = cvt4(rb00);
    *reinterpret_cast<ushort4*>(lB + srow * LDK + scol + 4)        = cvt4(rb01);
    *reinterpret_cast<ushort4*>(lB + (srow + 32) * LDK + scol)     = cvt4(rb10);
    *reinterpret_cast<ushort4*>(lB + (srow + 32) * LDK + scol + 4) = cvt4(rb11);
    __syncthreads();
    if (k0 + 64 < DIM) {  // prefetch next tile; MFMA hides latency
      const int k = k0 + 64;
      ra00 = *reinterpret_cast<const float4*>(aptr0 + k);
      ra01 = *reinterpret_cast<const float4*>(aptr0 + k + 4);
      ra10 = av1 ? *reinterpret_cast<const float4*>(aptr1 + k)     : z4;
      ra11 = av1 ? *reinterpret_cast<const float4*>(aptr1 + k + 4) : z4;
      rb00 = *reinterpret_cast<const float4*>(bptr0 + k);
      rb01 = *reinterpret_cast<const float4*>(bptr0 + k + 4);
      rb10 = *reinterpret_cast<const float4*>(bptr1 + k);
      rb11 = *reinterpret_cast<const float4*>(bptr1 + k + 4);
    }
#pragma unroll
    for (int kk = 0; kk < 64; kk += 32) {
      short8 a0 = *reinterpret_cast<const short8*>(lA + (wr * 32 + l16) * LDK + kk + quad * 8);
      short8 a1 = *reinterpret_cast<const short8*>(lA + (wr * 32 + 16 + l16) * LDK + kk + quad * 8);
      short8 b0 = *reinterpret_cast<const short8*>(lB + (wc * 32 + l16) * LDK + kk + quad * 8);
      short8 b1 = *reinterpret_cast<const short8*>(lB + (wc * 32 + 16 + l16) * LDK + kk + quad * 8);
      acc[0][0] = __builtin_amdgcn_mfma_f32_16x16x32_bf16(a0, b0, acc[0][0], 0, 0, 0);
      acc[0][1] = __builtin_amdgcn_mfma_f32_16x16x32_bf16(a0, b1, acc[0][1], 0, 0, 0);
      acc[1][0] = __builtin_amdgcn_mfma_f32_16x16x32_bf16(a1, b0, acc[1][0], 0, 0, 0);
      acc[1][1] = __builtin_amdgcn_mfma_f32_16x16x32_bf16(a1, b1, acc[1][1], 0, 0, 0);
    }
    __syncthreads();
  }

#pragma unroll
  for (int mi = 0; mi < 2; ++mi) {
#pragma unroll
    for (int ni = 0; ni < 2; ++ni) {
      const int gcol = bn0 + wc * 32 + ni * 16 + l16;
#pragma unroll
      for (int i = 0; i < 4; ++i) {
        const int grow = wr * 32 + mi * 16 + quad * 4 + i;
        if (grow < XROW - 1)  // rows 0..46
          O[(size_t)grow * DIM + gcol] = acc[mi][ni][i];
      }
    }
  }
}

// ---------------------------------------------------------------------------
// K2: fused gram48 + XvT transpose (disjoint blocks).
// Block 0:    G48[48,64] = [Xq;bq] · [Xk;bk]^T  (one 64x64 MFMA tile, K=1024)
// Blocks 1-64: XvT[n][k] = bf16(Xv[k][n]) for k<47 else 0  (1024 x 64 bf16)
// ---------------------------------------------------------------------------
__global__ __launch_bounds__(256) void gram_vexp(
    const float* __restrict__ Xq, const float* __restrict__ Xk,
    const float* __restrict__ bq, const float* __restrict__ bk,
    const float* __restrict__ Xv,
    float* __restrict__ G48, unsigned short* __restrict__ XvT) {
  const int tid = threadIdx.x;

  if (blockIdx.x == 0) {
    __shared__ __attribute__((aligned(16))) unsigned short lA[64 * LDK];
    __shared__ __attribute__((aligned(16))) unsigned short lB[64 * LDK];

    const int lane = tid & 63;
    const int wave = tid >> 6;
    const int wr   = wave >> 1;
    const int wc   = wave & 1;
    const int quad = lane >> 4;
    const int l16  = lane & 15;
    const int srow = tid >> 3;
    const int scol = (tid & 7) << 3;

    // half0 rows 0..31 <- Xq/Xk; half1: rows 32..46 <- Xq/Xk, row 47 <- bias
    const float* aptr0 = Xq + (size_t)srow * DIM + scol;
    const float* bptr0 = Xk + (size_t)srow * DIM + scol;
    const bool   v1    = (srow <= LW);
    const float* aptr1 = (srow < LW) ? (Xq + (size_t)(32 + srow) * DIM + scol)
                                     : (srow == LW ? (bq + scol) : Xq);
    const float* bptr1 = (srow < LW) ? (Xk + (size_t)(32 + srow) * DIM + scol)
                                     : (srow == LW ? (bk + scol) : Xk);

    const float4 z4 = make_float4(0.f, 0.f, 0.f, 0.f);
    float4 ra00 = *reinterpret_cast<const float4*>(aptr0);
    float4 ra01 = *reinterpret_cast<const float4*>(aptr0 + 4);
    float4 ra10 = v1 ? *reinterpret_cast<const float4*>(aptr1)     : z4;
    float4 ra11 = v1 ? *reinterpret_cast<const float4*>(aptr1 + 4) : z4;
    float4 rb00 = *reinterpret_cast<const float4*>(bptr0);
    float4 rb01 = *reinterpret_cast<const float4*>(bptr0 + 4);
    float4 rb10 = v1 ? *reinterpret_cast<const float4*>(bptr1)     : z4;
    float4 rb11 = v1 ? *reinterpret_cast<const float4*>(bptr1 + 4) : z4;

    floatx4 acc[2][2];
#pragma unroll
    for (int i = 0; i < 2; ++i)
#pragma unroll
      for (int j = 0; j < 2; ++j) acc[i][j] = (floatx4){0.f, 0.f, 0.f, 0.f};

    for (int k0 = 0; k0 < DIM; k0 += 64) {
      *reinterpret_cast<ushort4*>(lA + srow * LDK + scol)            = cvt4(ra00);
      *reinterpret_cast<ushort4*>(lA + srow * LDK + scol + 4)        = cvt4(ra01);
      *reinterpret_cast<ushort4*>(lA + (srow + 32) * LDK + scol)     = cvt4(ra10);
      *reinterpret_cast<ushort4*>(lA + (srow + 32) * LDK + scol + 4) = cvt4(ra11);
      *reinterpret_cast<ushort4*>(lB + srow * LDK + scol)            = cvt4(rb00);
      *reinterpret_cast<ushort4*>(lB + srow * LDK + scol + 4)        = cvt4(rb01);
      *reinterpret_cast<ushort4*>(lB + (srow + 32) * LDK + scol)     = cvt4(rb10);
      *reinterpret_cast<ushort4*>(lB + (srow + 32) * LDK + scol + 4) = cvt4(rb11);
      __syncthreads();
      if (k0 + 64 < DIM) {
        const int k = k0 + 64;
        ra00 = *reinterpret_cast<const float4*>(aptr0 + k);
        ra01 = *reinterpret_cast<const float4*>(aptr0 + k + 4);
        ra10 = v1 ? *reinterpret_cast<const float4*>(aptr1 + k)     : z4;
        ra11 = v1 ? *reinterpret_cast<const float4*>(aptr1 + k + 4) : z4;
        rb00 = *reinterpret_cast<const float4*>(bptr0 + k);
        rb01 = *reinterpret_cast<const float4*>(bptr0 + k + 4);
        rb10 = v1 ? *reinterpret_cast<const float4*>(bptr1 + k)     : z4;
        rb11 = v1 ? *reinterpret_cast<const float4*>(bptr1 + k + 4) : z4;
      }
#pragma unroll
      for (int kk = 0; kk < 64; kk += 32) {
        short8 a0 = *reinterpret_cast<const short8*>(lA + (wr * 32 + l16) * LDK + kk + quad * 8);
        short8 a1 = *reinterpret_cast<const short8*>(lA + (wr * 32 + 16 + l16) * LDK + kk + quad * 8);
        short8 b0 = *reinterpret_cast<const short8*>(lB + (wc * 32 + l16) * LDK + kk + quad * 8);
        short8 b1 = *reinterpret_cast<const short8*>(lB + (wc * 32 + 16 + l16) * LDK + kk + quad * 8);
        acc[0][0] = __builtin_amdgcn_mfma_f32_16x16x32_bf16(a0, b0, acc[0][0], 0, 0, 0);
        acc[0][1] = __builtin_amdgcn_mfma_f32_16x16x32_bf16(a0, b1, acc[0][1], 0, 0, 0);
        acc[1][0] = __builtin_amdgcn_mfma_f32_16x16x32_bf16(a1, b0, acc[1][0], 0, 0, 0);
        acc[1][1] = __builtin_amdgcn_mfma_f32_16x16x32_bf16(a1, b1, acc[1][1], 0, 0, 0);
      }
      __syncthreads();
    }

#pragma unroll
    for (int mi = 0; mi < 2; ++mi) {
#pragma unroll
      for (int ni = 0; ni < 2; ++ni) {
        const int gcol = wc * 32 + ni * 16 + l16;
#pragma unroll
        for (int i = 0; i < 4; ++i) {
          const int grow = wr * 32 + mi * 16 + quad * 4 + i;
          if (grow < XROW)
            G48[(size_t)grow * G48LD + gcol] = acc[mi][ni][i];
        }
      }
    }
  } else {
    // XvT build: 64 blocks x 256 thr; each thread one ushort4 of XvT.
    const int n  = ((int)blockIdx.x - 1) * 16 + (tid >> 4);
    const int k0 = (tid & 15) * 4;
    float v[4];
#pragma unroll
    for (int i = 0; i < 4; ++i) {
      const int k = k0 + i;
      v[i] = (k < XROW - 1) ? Xv[(size_t)k * DIM + n] : 0.f;
    }
    ushort4 o;
    o.x = f2b(v[0]); o.y = f2b(v[1]); o.z = f2b(v[2]); o.w = f2b(v[3]);
    *reinterpret_cast<ushort4*>(XvT + (size_t)n * 64 + k0) = o;
  }
}

// ---------------------------------------------------------------------------
// K3a: per-move softmax coefficients. 256 blocks x 16 moves; one move per
// 16-lane group; in-lane row softmax (lane = row l). Output C[4096][128] bf16:
// cols 0..63 = hi(coeff), cols 64..127 = lo(residual) — hi/lo split keeps the
// downstream bf16 GEMM numerically ~fp32 in the coefficients.
// coeff slots: [0,32) token-accumulated w, [32,47) position w, rest 0.
// ---------------------------------------------------------------------------
__global__ __launch_bounds__(256) void coef_k(
    const void* __restrict__ tokens_raw, const float* __restrict__ G48,
    unsigned short* __restrict__ C) {
  __shared__ float Gs[XROW * 65];       // padded LD=65: gather conflict-free
  __shared__ float Sm[16][LW][17];
  __shared__ float CL[16][64];
  __shared__ int   tokL[16][16];
  __shared__ int   is64_s;
  const int m0  = blockIdx.x * 16;
  const int tid = threadIdx.x;

  const unsigned int* u32 = (const unsigned int*)tokens_raw;
  if (tid < 64) {  // int64 tokens (<32) have all odd 32-bit words zero
    unsigned int v = u32[2 * tid + 1];
    unsigned long long nz = __ballot(v != 0);
    if (tid == 0) is64_s = (nz == 0ULL) ? 1 : 0;
  }
#pragma unroll
  for (int i = 0; i < 12; ++i) {        // stage 48x64 G48 into padded LDS
    const int idx = i * 256 + tid;
    Gs[(idx >> 6) * 65 + (idx & 63)] = G48[idx];
  }
  {
    const int g = tid >> 4, L = tid & 15;
#pragma unroll
    for (int i = 0; i < 4; ++i) CL[g][L * 4 + i] = 0.f;
  }
  __syncthreads();  // is64_s + Gs + CL visible

  if (tid < 16 * LW) {
    const int mv = tid / LW, j = tid - mv * LW;
    int t;
    if (is64_s) t = (int)((const long long*)tokens_raw)[(size_t)(m0 + mv) * LW + j];
    else        t = ((const int*)tokens_raw)[(size_t)(m0 + mv) * LW + j];
    tokL[mv][j] = t;
  }
  __syncthreads();

  const int g = tid >> 4;
  const int L = tid & 15;
  if (L < LW) {  // lane L = row l of move (m0+g)
    const int rb0 = tokL[g][L] * 65;
    const int rb1 = (32 + L) * 65;
    const int rb2 = (XROW - 1) * 65;
    float S[LW];
#pragma unroll
    for (int j = 0; j < LW; ++j) {
      const int c0 = tokL[g][j];
      const int c1 = 32 + j;
      S[j] = Gs[rb0 + c0] + Gs[rb1 + c0] + Gs[rb2 + c0]
           + Gs[rb0 + c1] + Gs[rb1 + c1] + Gs[rb2 + c1];
    }
    float mx = S[0];
#pragma unroll
    for (int j = 1; j < LW; ++j) mx = fmaxf(mx, S[j]);
    float sum = 0.f;
#pragma unroll
    for (int j = 0; j < LW; ++j) { S[j] = __expf(S[j] - mx); sum += S[j]; }
    const float inv = 1.0f / sum;
#pragma unroll
    for (int j = 0; j < LW; ++j) Sm[g][L][j] = S[j] * inv;
  }
  __syncthreads();

  if (L < LW) {  // lane L = column j: w_j = 2 * sum_l P[l][j], scatter
    float s = 0.f;
#pragma unroll
    for (int l = 0; l < LW; ++l) s += Sm[g][l][L];
    const float wj = 2.0f * s;
    atomicAdd(&CL[g][tokL[g][L]], wj);  // token slots may collide
    CL[g][32 + L] = wj;                 // position slots unique
  }
  __syncthreads();

  // hi/lo bf16 split, write C row (stride 128)
  float4 cv = *reinterpret_cast<const float4*>(&CL[g][L * 4]);
  ushort4 hi, lo;
  hi.x = f2b(cv.x); hi.y = f2b(cv.y); hi.z = f2b(cv.z); hi.w = f2b(cv.w);
  lo.x = f2b(cv.x - b2f(hi.x)); lo.y = f2b(cv.y - b2f(hi.y));
  lo.z = f2b(cv.z - b2f(hi.z)); lo.w = f2b(cv.w - b2f(hi.w));
  unsigned short* Crow = C + (size_t)(m0 + g) * 128;
  *reinterpret_cast<ushort4*>(Crow + L * 4)      = hi;
  *reinterpret_cast<ushort4*>(Crow + 64 + L * 4) = lo;
}

// ---------------------------------------------------------------------------
// K3b: out[4096,1024] = C · XvT + 30*bv.  K=64 (47 used), 64x64 tiles,
// 4 waves 2x2, 16 MFMA/block (hi+lo), direct global frag loads, no LDS.
// ---------------------------------------------------------------------------
__global__ __launch_bounds__(256) void out_gemm(
    const unsigned short* __restrict__ C, const unsigned short* __restrict__ XvT,
    const float* __restrict__ bv, float* __restrict__ out) {
  const int bm0 = blockIdx.x * 64;
  const int bn0 = blockIdx.y * 64;
  const int tid  = threadIdx.x;
  const int lane = tid & 63;
  const int wave = tid >> 6;
  const int wr   = wave >> 1;
  const int wc   = wave & 1;
  const int quad = lane >> 4;
  const int l16  = lane & 15;

  const unsigned short* A0 = C + (size_t)(bm0 + wr * 32 + l16) * 128;
  const unsigned short* A1 = A0 + 16 * 128;
  const unsigned short* B0 = XvT + (size_t)(bn0 + wc * 32 + l16) * 64;
  const unsigned short* B1 = B0 + 16 * 64;

  floatx4 acc[2][2];
#pragma unroll
  for (int i = 0; i < 2; ++i)
#pragma unroll
    for (int j = 0; j < 2; ++j) acc[i][j] = (floatx4){0.f, 0.f, 0.f, 0.f};

#pragma unroll
  for (int ks = 0; ks < 64; ks += 32) {
    short8 b0  = *reinterpret_cast<const short8*>(B0 + ks + quad * 8);
    short8 b1  = *reinterpret_cast<const short8*>(B1 + ks + quad * 8);
    short8 a0h = *reinterpret_cast<const short8*>(A0 + ks + quad * 8);
    short8 a1h = *reinterpret_cast<const short8*>(A1 + ks + quad * 8);
    short8 a0l = *reinterpret_cast<const short8*>(A0 + 64 + ks + quad * 8);
    short8 a1l = *reinterpret_cast<const short8*>(A1 + 64 + ks + quad * 8);
    acc[0][0] = __builtin_amdgcn_mfma_f32_16x16x32_bf16(a0h, b0, acc[0][0], 0, 0, 0);
    acc[0][0] = __builtin_amdgcn_mfma_f32_16x16x32_bf16(a0l, b0, acc[0][0], 0, 0, 0);
    acc[0][1] = __builtin_amdgcn_mfma_f32_16x16x32_bf16(a0h, b1, acc[0][1], 0, 0, 0);
    acc[0][1] = __builtin_amdgcn_mfma_f32_16x16x32_bf16(a0l, b1, acc[0][1], 0, 0, 0);
    acc[1][0] = __builtin_amdgcn_mfma_f32_16x16x32_bf16(a1h, b0, acc[1][0], 0, 0, 0);
    acc[1][0] = __builtin_amdgcn_mfma_f32_16x16x32_bf16(a1l, b0, acc[1][0], 0, 0, 0);
    acc[1][1] = __builtin_amdgcn_mfma_f32_16x16x32_bf16(a1h, b1, acc[1][1], 0, 0, 0);
    acc[1][1] = __builtin_amdgcn_mfma_f32_16x16x32_bf16(a1l, b1, acc[1][1], 0, 0, 0);
  }

#pragma unroll
  for (int mi = 0; mi < 2; ++mi) {
#pragma unroll
    for (int ni = 0; ni < 2; ++ni) {
      const int gcol = bn0 + wc * 32 + ni * 16 + l16;
      const float bias30 = 30.0f * bv[gcol];
#pragma unroll
      for (int i = 0; i < 4; ++i) {
        const int grow = bm0 + wr * 32 + mi * 16 + quad * 4 + i;
        out[(size_t)grow * DIM + gcol] = acc[mi][ni][i] + bias30;
      }
    }
  }
}

// ---------------------------------------------------------------------------
extern "C" void kernel_launch(void* const* d_in, const int* in_sizes, int n_in,
                              void* d_out, int out_size, void* d_ws, size_t ws_size,
                              hipStream_t stream) {
  const void*  tokens = d_in[0];
  const float* letter = (const float*)d_in[1];
  const float* pos    = (const float*)d_in[2];
  const float* Wq     = (const float*)d_in[3];
  const float* bq     = (const float*)d_in[4];
  const float* Wk     = (const float*)d_in[5];
  const float* bk     = (const float*)d_in[6];
  const float* Wv     = (const float*)d_in[7];
  const float* bv     = (const float*)d_in[8];
  float*       outp   = (float*)d_out;   // reference output dtype = float32

  char* ws = (char*)d_ws;
  const size_t XSZ  = (size_t)XROW * DIM * 4;      // 192 KB each
  const size_t GSZ  = (size_t)XROW * G48LD * 4;    // 12 KB (rounded region 16K)
  float* Xq = (float*)(ws);
  float* Xk = (float*)(ws + XSZ);
  float* Xv = (float*)(ws + 2 * XSZ);
  float* Gp = (float*)(ws + 3 * XSZ);
  unsigned short* XvT = (unsigned short*)(ws + 3 * XSZ + 16384);
  unsigned short* Cc  = (unsigned short*)(ws + 3 * XSZ + 16384 + (size_t)DIM * 64 * 2);
  (void)GSZ;

  proj_small<<<dim3(1, 16, 3), 256, 0, stream>>>(letter, pos, Wq, Wk, Wv,
                                                 Xq, Xk, Xv);
  gram_vexp<<<65, 256, 0, stream>>>(Xq, Xk, bq, bk, Xv, Gp, XvT);
  coef_k<<<NMOVES / 16, 256, 0, stream>>>(tokens, Gp, Cc);
  out_gemm<<<dim3(NMOVES / 64, DIM / 64), 256, 0, stream>>>(Cc, XvT, bv, outp);
}

// Round 4
// 118.662 us; speedup vs baseline: 1.1587x; 1.1524x over previous
//
#include <hip/hip_runtime.h>
#include <hip/hip_bf16.h>

// Shapes (fixed by the problem)
#define NMOVES 4096
#define LW     15
#define DIM    1024
#define VOC    32
#define XROW   48    // [letter(32); pos(15); bias(1)] factored rows
#define KSPL   4     // proj K-split (256-wide chunks)
#define GSPL   8     // gram K-split (128-wide chunks)
#define PLSZ   (48 * DIM)        // one proj partial plane (fp32 elems)
#define GPLSZ  (48 * 64)         // one gram partial plane (fp32 elems)

typedef __attribute__((ext_vector_type(8))) short  short8;   // 8 bf16
typedef __attribute__((ext_vector_type(4))) float  floatx4;  // MFMA C/D

__device__ __forceinline__ unsigned short f2b(float f) {
  unsigned int x;
  __builtin_memcpy(&x, &f, 4);
  x = x + 0x7FFFu + ((x >> 16) & 1u);  // round-to-nearest-even
  return (unsigned short)(x >> 16);
}
__device__ __forceinline__ float b2f(unsigned short u) {
  unsigned int x = ((unsigned int)u) << 16;
  float f;
  __builtin_memcpy(&f, &x, 4);
  return f;
}
__device__ __forceinline__ short8 pk8(float4 a, float4 b) {
  short8 r;
  r[0] = (short)f2b(a.x); r[1] = (short)f2b(a.y);
  r[2] = (short)f2b(a.z); r[3] = (short)f2b(a.w);
  r[4] = (short)f2b(b.x); r[5] = (short)f2b(b.y);
  r[6] = (short)f2b(b.z); r[7] = (short)f2b(b.w);
  return r;
}
__device__ __forceinline__ float4 ld4(const float* p) {
  return *reinterpret_cast<const float4*>(p);
}

// ---------------------------------------------------------------------------
// K1: factored projection, K-split 4, direct-fragment (no LDS, no barriers).
// Xp[z][p][r<47][1024] = sum_{k in chunk p} bf16(X[r][k])*bf16(W_z[c][k])
// X = [letter(32); pos(15)]; rows 47..63 zero. Grid (4,16,3), 256 thr.
// ---------------------------------------------------------------------------
__global__ __launch_bounds__(256) void proj_ksplit(
    const float* __restrict__ letter, const float* __restrict__ pos,
    const float* __restrict__ Wq, const float* __restrict__ Wk,
    const float* __restrict__ Wv, float* __restrict__ Xp) {
  const int p     = blockIdx.x;        // K chunk (256 wide)
  const int bn0   = blockIdx.y * 64;   // col tile
  const int z     = blockIdx.z;
  const int kbase = p * 256;
  const float* W = (z == 0) ? Wq : (z == 1) ? Wk : Wv;
  float*       O = Xp + (size_t)(z * KSPL + p) * PLSZ;

  const int tid  = threadIdx.x;
  const int lane = tid & 63;
  const int wave = tid >> 6;
  const int wr   = wave >> 1;
  const int wc   = wave & 1;
  const int quad = lane >> 4;
  const int l16  = lane & 15;

  // per-lane A row sources (row 0..31 letter, 32..46 pos, else zero)
  const int rA0 = wr * 32 + l16;
  const int rA1 = rA0 + 16;
  const float* a0p = (rA0 < 32) ? letter + (size_t)rA0 * DIM
                   : (rA0 < 47) ? pos + (size_t)(rA0 - 32) * DIM : nullptr;
  const float* a1p = (rA1 < 32) ? letter + (size_t)rA1 * DIM
                   : (rA1 < 47) ? pos + (size_t)(rA1 - 32) * DIM : nullptr;
  const float* b0p = W + (size_t)(bn0 + wc * 32 + l16) * DIM;
  const float* b1p = b0p + (size_t)16 * DIM;

  floatx4 acc[2][2];
#pragma unroll
  for (int i = 0; i < 2; ++i)
#pragma unroll
    for (int j = 0; j < 2; ++j) acc[i][j] = (floatx4){0.f, 0.f, 0.f, 0.f};

  const short8 z8 = (short8){0,0,0,0,0,0,0,0};
#pragma unroll
  for (int kk = 0; kk < 256; kk += 32) {
    const int kc = kbase + kk + quad * 8;
    short8 a0 = a0p ? pk8(ld4(a0p + kc), ld4(a0p + kc + 4)) : z8;
    short8 a1 = a1p ? pk8(ld4(a1p + kc), ld4(a1p + kc + 4)) : z8;
    short8 b0 = pk8(ld4(b0p + kc), ld4(b0p + kc + 4));
    short8 b1 = pk8(ld4(b1p + kc), ld4(b1p + kc + 4));
    acc[0][0] = __builtin_amdgcn_mfma_f32_16x16x32_bf16(a0, b0, acc[0][0], 0, 0, 0);
    acc[0][1] = __builtin_amdgcn_mfma_f32_16x16x32_bf16(a0, b1, acc[0][1], 0, 0, 0);
    acc[1][0] = __builtin_amdgcn_mfma_f32_16x16x32_bf16(a1, b0, acc[1][0], 0, 0, 0);
    acc[1][1] = __builtin_amdgcn_mfma_f32_16x16x32_bf16(a1, b1, acc[1][1], 0, 0, 0);
  }

#pragma unroll
  for (int mi = 0; mi < 2; ++mi) {
#pragma unroll
    for (int ni = 0; ni < 2; ++ni) {
      const int gcol = bn0 + wc * 32 + ni * 16 + l16;
#pragma unroll
      for (int i = 0; i < 4; ++i) {
        const int grow = wr * 32 + mi * 16 + quad * 4 + i;
        if (grow < 47)
          O[(size_t)grow * DIM + gcol] = acc[mi][ni][i];
      }
    }
  }
}

// ---------------------------------------------------------------------------
// K2: fused gram (K-split 8, blocks 0..7) + XvT transpose (blocks 8..23).
// Gram: Gp8[b][48][64] = [Xq;bq]·[Xk;bk]^T over K chunk b (128 wide),
//       A/B fragments built by summing the 4 proj planes in-registers.
// XvT:  XvT[n][k] = bf16(sum_p Xvp[p][k][n]), k<47 else 0.  (1024 x 64)
// No LDS, no barriers anywhere.
// ---------------------------------------------------------------------------
__device__ __forceinline__ short8 gfrag(const float* __restrict__ X4,
                                        const float* __restrict__ bias,
                                        int row, int kc) {
  if (row < 47) {
    const float* r0 = X4 + (size_t)row * DIM + kc;
    float4 s0 = ld4(r0),            s1 = ld4(r0 + 4);
    float4 t0 = ld4(r0 + PLSZ),     t1 = ld4(r0 + PLSZ + 4);
    float4 u0 = ld4(r0 + 2 * PLSZ), u1 = ld4(r0 + 2 * PLSZ + 4);
    float4 v0 = ld4(r0 + 3 * PLSZ), v1 = ld4(r0 + 3 * PLSZ + 4);
    s0.x += t0.x + u0.x + v0.x; s0.y += t0.y + u0.y + v0.y;
    s0.z += t0.z + u0.z + v0.z; s0.w += t0.w + u0.w + v0.w;
    s1.x += t1.x + u1.x + v1.x; s1.y += t1.y + u1.y + v1.y;
    s1.z += t1.z + u1.z + v1.z; s1.w += t1.w + u1.w + v1.w;
    return pk8(s0, s1);
  } else if (row == 47) {
    return pk8(ld4(bias + kc), ld4(bias + kc + 4));
  }
  return (short8){0,0,0,0,0,0,0,0};
}

__global__ __launch_bounds__(256) void gram_vexp(
    const float* __restrict__ Xp,
    const float* __restrict__ bq, const float* __restrict__ bk,
    float* __restrict__ Gp8, unsigned short* __restrict__ XvT) {
  const int bid = blockIdx.x;
  const int tid = threadIdx.x;

  if (bid < GSPL) {
    const int kbase = bid * 128;
    const int lane = tid & 63;
    const int wave = tid >> 6;
    const int wr   = wave >> 1;
    const int wc   = wave & 1;
    const int quad = lane >> 4;
    const int l16  = lane & 15;

    const float* Xq4 = Xp;                       // planes 0..3
    const float* Xk4 = Xp + (size_t)4 * PLSZ;    // planes 4..7
    const int rA0 = wr * 32 + l16, rA1 = rA0 + 16;
    const int rB0 = wc * 32 + l16, rB1 = rB0 + 16;

    floatx4 acc[2][2];
#pragma unroll
    for (int i = 0; i < 2; ++i)
#pragma unroll
      for (int j = 0; j < 2; ++j) acc[i][j] = (floatx4){0.f, 0.f, 0.f, 0.f};

#pragma unroll
    for (int kk = 0; kk < 128; kk += 32) {
      const int kc = kbase + kk + quad * 8;
      short8 a0 = gfrag(Xq4, bq, rA0, kc);
      short8 a1 = gfrag(Xq4, bq, rA1, kc);
      short8 b0 = gfrag(Xk4, bk, rB0, kc);
      short8 b1 = gfrag(Xk4, bk, rB1, kc);
      acc[0][0] = __builtin_amdgcn_mfma_f32_16x16x32_bf16(a0, b0, acc[0][0], 0, 0, 0);
      acc[0][1] = __builtin_amdgcn_mfma_f32_16x16x32_bf16(a0, b1, acc[0][1], 0, 0, 0);
      acc[1][0] = __builtin_amdgcn_mfma_f32_16x16x32_bf16(a1, b0, acc[1][0], 0, 0, 0);
      acc[1][1] = __builtin_amdgcn_mfma_f32_16x16x32_bf16(a1, b1, acc[1][1], 0, 0, 0);
    }

    float* Gout = Gp8 + (size_t)bid * GPLSZ;
#pragma unroll
    for (int mi = 0; mi < 2; ++mi) {
#pragma unroll
      for (int ni = 0; ni < 2; ++ni) {
        const int gcol = wc * 32 + ni * 16 + l16;
#pragma unroll
        for (int i = 0; i < 4; ++i) {
          const int grow = wr * 32 + mi * 16 + quad * 4 + i;
          if (grow < XROW)
            Gout[(size_t)grow * 64 + gcol] = acc[mi][ni][i];
        }
      }
    }
  } else {
    // XvT build: 16 blocks; lane<->n coalesced plane reads.
    const int n  = (bid - GSPL) * 64 + (tid & 63);
    const int kg = tid >> 6;
    const float* Xv4 = Xp + (size_t)8 * PLSZ;    // planes 8..11
#pragma unroll
    for (int s = 0; s < 4; ++s) {
      const int k0 = kg * 4 + s * 16;
      ushort4 o;
      unsigned short* oc = &o.x;
#pragma unroll
      for (int i = 0; i < 4; ++i) {
        const int k = k0 + i;
        float v = 0.f;
        if (k < 47) {
          const size_t off = (size_t)k * DIM + n;
          v = Xv4[off] + Xv4[off + PLSZ] + Xv4[off + 2 * PLSZ] +
              Xv4[off + 3 * PLSZ];
        }
        oc[i] = f2b(v);
      }
      *reinterpret_cast<ushort4*>(XvT + (size_t)n * 64 + k0) = o;
    }
  }
}

// ---------------------------------------------------------------------------
// K3: per-move softmax coefficients. 256 blocks x 16 moves; one move per
// 16-lane group; in-lane row softmax (lane = row l). Output C[4096][128] bf16:
// cols 0..63 = hi(coeff), cols 64..127 = lo(residual).
// Stages G = sum of the 8 gram partial planes into padded LDS.
// ---------------------------------------------------------------------------
__global__ __launch_bounds__(256) void coef_k(
    const void* __restrict__ tokens_raw, const float* __restrict__ Gp8,
    unsigned short* __restrict__ C) {
  __shared__ float Gs[XROW * 65];       // padded LD=65: gather conflict-free
  __shared__ float Sm[16][LW][17];
  __shared__ float CL[16][64];
  __shared__ int   tokL[16][16];
  __shared__ int   is64_s;
  const int m0  = blockIdx.x * 16;
  const int tid = threadIdx.x;

  const unsigned int* u32 = (const unsigned int*)tokens_raw;
  if (tid < 64) {  // int64 tokens (<32) have all odd 32-bit words zero
    unsigned int v = u32[2 * tid + 1];
    unsigned long long nz = __ballot(v != 0);
    if (tid == 0) is64_s = (nz == 0ULL) ? 1 : 0;
  }
#pragma unroll
  for (int i = 0; i < 12; ++i) {        // stage sum of 8 planes (48x64)
    const int idx = i * 256 + tid;
    float s = 0.f;
#pragma unroll
    for (int p = 0; p < GSPL; ++p) s += Gp8[(size_t)p * GPLSZ + idx];
    Gs[(idx >> 6) * 65 + (idx & 63)] = s;
  }
  {
    const int g = tid >> 4, L = tid & 15;
#pragma unroll
    for (int i = 0; i < 4; ++i) CL[g][L * 4 + i] = 0.f;
  }
  __syncthreads();  // is64_s + Gs + CL visible

  if (tid < 16 * LW) {
    const int mv = tid / LW, j = tid - mv * LW;
    int t;
    if (is64_s) t = (int)((const long long*)tokens_raw)[(size_t)(m0 + mv) * LW + j];
    else        t = ((const int*)tokens_raw)[(size_t)(m0 + mv) * LW + j];
    tokL[mv][j] = t;
  }
  __syncthreads();

  const int g = tid >> 4;
  const int L = tid & 15;
  if (L < LW) {  // lane L = row l of move (m0+g)
    const int rb0 = tokL[g][L] * 65;
    const int rb1 = (32 + L) * 65;
    const int rb2 = (XROW - 1) * 65;
    float S[LW];
#pragma unroll
    for (int j = 0; j < LW; ++j) {
      const int c0 = tokL[g][j];
      const int c1 = 32 + j;
      S[j] = Gs[rb0 + c0] + Gs[rb1 + c0] + Gs[rb2 + c0]
           + Gs[rb0 + c1] + Gs[rb1 + c1] + Gs[rb2 + c1];
    }
    float mx = S[0];
#pragma unroll
    for (int j = 1; j < LW; ++j) mx = fmaxf(mx, S[j]);
    float sum = 0.f;
#pragma unroll
    for (int j = 0; j < LW; ++j) { S[j] = __expf(S[j] - mx); sum += S[j]; }
    const float inv = 1.0f / sum;
#pragma unroll
    for (int j = 0; j < LW; ++j) Sm[g][L][j] = S[j] * inv;
  }
  __syncthreads();

  if (L < LW) {  // lane L = column j: w_j = 2 * sum_l P[l][j], scatter
    float s = 0.f;
#pragma unroll
    for (int l = 0; l < LW; ++l) s += Sm[g][l][L];
    const float wj = 2.0f * s;
    atomicAdd(&CL[g][tokL[g][L]], wj);  // token slots may collide
    CL[g][32 + L] = wj;                 // position slots unique
  }
  __syncthreads();

  // hi/lo bf16 split, write C row (stride 128)
  float4 cv = *reinterpret_cast<const float4*>(&CL[g][L * 4]);
  ushort4 hi, lo;
  hi.x = f2b(cv.x); hi.y = f2b(cv.y); hi.z = f2b(cv.z); hi.w = f2b(cv.w);
  lo.x = f2b(cv.x - b2f(hi.x)); lo.y = f2b(cv.y - b2f(hi.y));
  lo.z = f2b(cv.z - b2f(hi.z)); lo.w = f2b(cv.w - b2f(hi.w));
  unsigned short* Crow = C + (size_t)(m0 + g) * 128;
  *reinterpret_cast<ushort4*>(Crow + L * 4)      = hi;
  *reinterpret_cast<ushort4*>(Crow + 64 + L * 4) = lo;
}

// ---------------------------------------------------------------------------
// K3b: out[4096,1024] = C · XvT + 30*bv.  K=64 (47 used), 64x64 tiles,
// 4 waves 2x2, 16 MFMA/block (hi+lo), direct global frag loads, no LDS.
// ---------------------------------------------------------------------------
__global__ __launch_bounds__(256) void out_gemm(
    const unsigned short* __restrict__ C, const unsigned short* __restrict__ XvT,
    const float* __restrict__ bv, float* __restrict__ out) {
  const int bm0 = blockIdx.x * 64;
  const int bn0 = blockIdx.y * 64;
  const int tid  = threadIdx.x;
  const int lane = tid & 63;
  const int wave = tid >> 6;
  const int wr   = wave >> 1;
  const int wc   = wave & 1;
  const int quad = lane >> 4;
  const int l16  = lane & 15;

  const unsigned short* A0 = C + (size_t)(bm0 + wr * 32 + l16) * 128;
  const unsigned short* A1 = A0 + 16 * 128;
  const unsigned short* B0 = XvT + (size_t)(bn0 + wc * 32 + l16) * 64;
  const unsigned short* B1 = B0 + 16 * 64;

  floatx4 acc[2][2];
#pragma unroll
  for (int i = 0; i < 2; ++i)
#pragma unroll
    for (int j = 0; j < 2; ++j) acc[i][j] = (floatx4){0.f, 0.f, 0.f, 0.f};

#pragma unroll
  for (int ks = 0; ks < 64; ks += 32) {
    short8 b0  = *reinterpret_cast<const short8*>(B0 + ks + quad * 8);
    short8 b1  = *reinterpret_cast<const short8*>(B1 + ks + quad * 8);
    short8 a0h = *reinterpret_cast<const short8*>(A0 + ks + quad * 8);
    short8 a1h = *reinterpret_cast<const short8*>(A1 + ks + quad * 8);
    short8 a0l = *reinterpret_cast<const short8*>(A0 + 64 + ks + quad * 8);
    short8 a1l = *reinterpret_cast<const short8*>(A1 + 64 + ks + quad * 8);
    acc[0][0] = __builtin_amdgcn_mfma_f32_16x16x32_bf16(a0h, b0, acc[0][0], 0, 0, 0);
    acc[0][0] = __builtin_amdgcn_mfma_f32_16x16x32_bf16(a0l, b0, acc[0][0], 0, 0, 0);
    acc[0][1] = __builtin_amdgcn_mfma_f32_16x16x32_bf16(a0h, b1, acc[0][1], 0, 0, 0);
    acc[0][1] = __builtin_amdgcn_mfma_f32_16x16x32_bf16(a0l, b1, acc[0][1], 0, 0, 0);
    acc[1][0] = __builtin_amdgcn_mfma_f32_16x16x32_bf16(a1h, b0, acc[1][0], 0, 0, 0);
    acc[1][0] = __builtin_amdgcn_mfma_f32_16x16x32_bf16(a1l, b0, acc[1][0], 0, 0, 0);
    acc[1][1] = __builtin_amdgcn_mfma_f32_16x16x32_bf16(a1h, b1, acc[1][1], 0, 0, 0);
    acc[1][1] = __builtin_amdgcn_mfma_f32_16x16x32_bf16(a1l, b1, acc[1][1], 0, 0, 0);
  }

#pragma unroll
  for (int mi = 0; mi < 2; ++mi) {
#pragma unroll
    for (int ni = 0; ni < 2; ++ni) {
      const int gcol = bn0 + wc * 32 + ni * 16 + l16;
      const float bias30 = 30.0f * bv[gcol];
#pragma unroll
      for (int i = 0; i < 4; ++i) {
        const int grow = bm0 + wr * 32 + mi * 16 + quad * 4 + i;
        out[(size_t)grow * DIM + gcol] = acc[mi][ni][i] + bias30;
      }
    }
  }
}

// ---------------------------------------------------------------------------
extern "C" void kernel_launch(void* const* d_in, const int* in_sizes, int n_in,
                              void* d_out, int out_size, void* d_ws, size_t ws_size,
                              hipStream_t stream) {
  const void*  tokens = d_in[0];
  const float* letter = (const float*)d_in[1];
  const float* pos    = (const float*)d_in[2];
  const float* Wq     = (const float*)d_in[3];
  const float* bq     = (const float*)d_in[4];
  const float* Wk     = (const float*)d_in[5];
  const float* bk     = (const float*)d_in[6];
  const float* Wv     = (const float*)d_in[7];
  const float* bv     = (const float*)d_in[8];
  float*       outp   = (float*)d_out;   // reference output dtype = float32

  char* ws = (char*)d_ws;
  const size_t XP_SZ  = (size_t)12 * PLSZ * 4;      // 12 planes  = 2.25 MB
  const size_t GP_SZ  = (size_t)GSPL * GPLSZ * 4;   // 8 planes   = 96 KB
  const size_t XVT_SZ = (size_t)DIM * 64 * 2;       // 128 KB
  float*          Xp  = (float*)(ws);
  float*          Gp  = (float*)(ws + XP_SZ);
  unsigned short* XvT = (unsigned short*)(ws + XP_SZ + GP_SZ);
  unsigned short* Cc  = (unsigned short*)(ws + XP_SZ + GP_SZ + XVT_SZ);

  proj_ksplit<<<dim3(KSPL, 16, 3), 256, 0, stream>>>(letter, pos, Wq, Wk, Wv, Xp);
  gram_vexp<<<GSPL + 16, 256, 0, stream>>>(Xp, bq, bk, Gp, XvT);
  coef_k<<<NMOVES / 16, 256, 0, stream>>>(tokens, Gp, Cc);
  out_gemm<<<dim3(NMOVES / 64, DIM / 64), 256, 0, stream>>>(Cc, XvT, bv, outp);
}

// Round 5
// 113.884 us; speedup vs baseline: 1.2073x; 1.0419x over previous
//
#include <hip/hip_runtime.h>
#include <hip/hip_bf16.h>

// Shapes (fixed by the problem)
#define NMOVES 4096
#define LW     15
#define DIM    1024
#define VOC    32
#define XROW   48    // [letter(32); pos(15); bias(1)] factored rows
#define KSPL   4     // proj K-split (256-wide chunks)
#define GSPL   8     // gram K-split (128-wide chunks)
#define PLSZ   (48 * DIM)        // one proj partial plane (fp32 elems)

typedef __attribute__((ext_vector_type(8))) short  short8;   // 8 bf16
typedef __attribute__((ext_vector_type(4))) float  floatx4;  // MFMA C/D

__device__ __forceinline__ unsigned short f2b(float f) {
  unsigned int x;
  __builtin_memcpy(&x, &f, 4);
  x = x + 0x7FFFu + ((x >> 16) & 1u);  // round-to-nearest-even
  return (unsigned short)(x >> 16);
}
__device__ __forceinline__ float b2f(unsigned short u) {
  unsigned int x = ((unsigned int)u) << 16;
  float f;
  __builtin_memcpy(&f, &x, 4);
  return f;
}
__device__ __forceinline__ short8 pk8(float4 a, float4 b) {
  short8 r;
  r[0] = (short)f2b(a.x); r[1] = (short)f2b(a.y);
  r[2] = (short)f2b(a.z); r[3] = (short)f2b(a.w);
  r[4] = (short)f2b(b.x); r[5] = (short)f2b(b.y);
  r[6] = (short)f2b(b.z); r[7] = (short)f2b(b.w);
  return r;
}
__device__ __forceinline__ float4 ld4(const float* p) {
  return *reinterpret_cast<const float4*>(p);
}

// ---------------------------------------------------------------------------
// K1: factored projection, K-split 4, direct-fragment (no LDS, no barriers).
// Xp[z][p][r<47][1024] = sum_{k in chunk p} bf16(X[r][k])*bf16(W_z[c][k])
// X = [letter(32); pos(15)]; rows 47..63 zero. Grid (4,16,3), 256 thr.
// Block (0,0,0) additionally zeroes the G48 accumulation plane.
// ---------------------------------------------------------------------------
__global__ __launch_bounds__(256) void proj_ksplit(
    const float* __restrict__ letter, const float* __restrict__ pos,
    const float* __restrict__ Wq, const float* __restrict__ Wk,
    const float* __restrict__ Wv, float* __restrict__ Xp,
    float* __restrict__ G48) {
  const int tid = threadIdx.x;
  if (blockIdx.x == 0 && blockIdx.y == 0 && blockIdx.z == 0) {
#pragma unroll
    for (int i = 0; i < (XROW * 64) / 256; ++i) G48[i * 256 + tid] = 0.f;
  }

  const int p     = blockIdx.x;        // K chunk (256 wide)
  const int bn0   = blockIdx.y * 64;   // col tile
  const int z     = blockIdx.z;
  const int kbase = p * 256;
  const float* W = (z == 0) ? Wq : (z == 1) ? Wk : Wv;
  float*       O = Xp + (size_t)(z * KSPL + p) * PLSZ;

  const int lane = tid & 63;
  const int wave = tid >> 6;
  const int wr   = wave >> 1;
  const int wc   = wave & 1;
  const int quad = lane >> 4;
  const int l16  = lane & 15;

  // per-lane A row sources (row 0..31 letter, 32..46 pos, else zero)
  const int rA0 = wr * 32 + l16;
  const int rA1 = rA0 + 16;
  const float* a0p = (rA0 < 32) ? letter + (size_t)rA0 * DIM
                   : (rA0 < 47) ? pos + (size_t)(rA0 - 32) * DIM : nullptr;
  const float* a1p = (rA1 < 32) ? letter + (size_t)rA1 * DIM
                   : (rA1 < 47) ? pos + (size_t)(rA1 - 32) * DIM : nullptr;
  const float* b0p = W + (size_t)(bn0 + wc * 32 + l16) * DIM;
  const float* b1p = b0p + (size_t)16 * DIM;

  floatx4 acc[2][2];
#pragma unroll
  for (int i = 0; i < 2; ++i)
#pragma unroll
    for (int j = 0; j < 2; ++j) acc[i][j] = (floatx4){0.f, 0.f, 0.f, 0.f};

  const short8 z8 = (short8){0,0,0,0,0,0,0,0};
#pragma unroll
  for (int kk = 0; kk < 256; kk += 32) {
    const int kc = kbase + kk + quad * 8;
    short8 a0 = a0p ? pk8(ld4(a0p + kc), ld4(a0p + kc + 4)) : z8;
    short8 a1 = a1p ? pk8(ld4(a1p + kc), ld4(a1p + kc + 4)) : z8;
    short8 b0 = pk8(ld4(b0p + kc), ld4(b0p + kc + 4));
    short8 b1 = pk8(ld4(b1p + kc), ld4(b1p + kc + 4));
    acc[0][0] = __builtin_amdgcn_mfma_f32_16x16x32_bf16(a0, b0, acc[0][0], 0, 0, 0);
    acc[0][1] = __builtin_amdgcn_mfma_f32_16x16x32_bf16(a0, b1, acc[0][1], 0, 0, 0);
    acc[1][0] = __builtin_amdgcn_mfma_f32_16x16x32_bf16(a1, b0, acc[1][0], 0, 0, 0);
    acc[1][1] = __builtin_amdgcn_mfma_f32_16x16x32_bf16(a1, b1, acc[1][1], 0, 0, 0);
  }

#pragma unroll
  for (int mi = 0; mi < 2; ++mi) {
#pragma unroll
    for (int ni = 0; ni < 2; ++ni) {
      const int gcol = bn0 + wc * 32 + ni * 16 + l16;
#pragma unroll
      for (int i = 0; i < 4; ++i) {
        const int grow = wr * 32 + mi * 16 + quad * 4 + i;
        if (grow < 47)
          O[(size_t)grow * DIM + gcol] = acc[mi][ni][i];
      }
    }
  }
}

// ---------------------------------------------------------------------------
// K2: fused gram (K-split 8, blocks 0..7) + XvT transpose (blocks 8..23).
// Gram: atomicAdd into single G48[48][64] = [Xq;bq]·[Xk;bk]^T, per-K-chunk
//       partials; A/B fragments built by summing the 4 proj planes in-regs.
// XvT:  XvT[n][k] = bf16(sum_p Xvp[p][k][n]), k<47 else 0.  (1024 x 64)
// No LDS, no barriers anywhere.
// ---------------------------------------------------------------------------
__device__ __forceinline__ short8 gfrag(const float* __restrict__ X4,
                                        const float* __restrict__ bias,
                                        int row, int kc) {
  if (row < 47) {
    const float* r0 = X4 + (size_t)row * DIM + kc;
    float4 s0 = ld4(r0),            s1 = ld4(r0 + 4);
    float4 t0 = ld4(r0 + PLSZ),     t1 = ld4(r0 + PLSZ + 4);
    float4 u0 = ld4(r0 + 2 * PLSZ), u1 = ld4(r0 + 2 * PLSZ + 4);
    float4 v0 = ld4(r0 + 3 * PLSZ), v1 = ld4(r0 + 3 * PLSZ + 4);
    s0.x += t0.x + u0.x + v0.x; s0.y += t0.y + u0.y + v0.y;
    s0.z += t0.z + u0.z + v0.z; s0.w += t0.w + u0.w + v0.w;
    s1.x += t1.x + u1.x + v1.x; s1.y += t1.y + u1.y + v1.y;
    s1.z += t1.z + u1.z + v1.z; s1.w += t1.w + u1.w + v1.w;
    return pk8(s0, s1);
  } else if (row == 47) {
    return pk8(ld4(bias + kc), ld4(bias + kc + 4));
  }
  return (short8){0,0,0,0,0,0,0,0};
}

__global__ __launch_bounds__(256) void gram_vexp(
    const float* __restrict__ Xp,
    const float* __restrict__ bq, const float* __restrict__ bk,
    float* __restrict__ G48, unsigned short* __restrict__ XvT) {
  const int bid = blockIdx.x;
  const int tid = threadIdx.x;

  if (bid < GSPL) {
    const int kbase = bid * 128;
    const int lane = tid & 63;
    const int wave = tid >> 6;
    const int wr   = wave >> 1;
    const int wc   = wave & 1;
    const int quad = lane >> 4;
    const int l16  = lane & 15;

    const float* Xq4 = Xp;                       // planes 0..3
    const float* Xk4 = Xp + (size_t)4 * PLSZ;    // planes 4..7
    const int rA0 = wr * 32 + l16, rA1 = rA0 + 16;
    const int rB0 = wc * 32 + l16, rB1 = rB0 + 16;

    floatx4 acc[2][2];
#pragma unroll
    for (int i = 0; i < 2; ++i)
#pragma unroll
      for (int j = 0; j < 2; ++j) acc[i][j] = (floatx4){0.f, 0.f, 0.f, 0.f};

#pragma unroll
    for (int kk = 0; kk < 128; kk += 32) {
      const int kc = kbase + kk + quad * 8;
      short8 a0 = gfrag(Xq4, bq, rA0, kc);
      short8 a1 = gfrag(Xq4, bq, rA1, kc);
      short8 b0 = gfrag(Xk4, bk, rB0, kc);
      short8 b1 = gfrag(Xk4, bk, rB1, kc);
      acc[0][0] = __builtin_amdgcn_mfma_f32_16x16x32_bf16(a0, b0, acc[0][0], 0, 0, 0);
      acc[0][1] = __builtin_amdgcn_mfma_f32_16x16x32_bf16(a0, b1, acc[0][1], 0, 0, 0);
      acc[1][0] = __builtin_amdgcn_mfma_f32_16x16x32_bf16(a1, b0, acc[1][0], 0, 0, 0);
      acc[1][1] = __builtin_amdgcn_mfma_f32_16x16x32_bf16(a1, b1, acc[1][1], 0, 0, 0);
    }

#pragma unroll
    for (int mi = 0; mi < 2; ++mi) {
#pragma unroll
      for (int ni = 0; ni < 2; ++ni) {
        const int gcol = wc * 32 + ni * 16 + l16;
#pragma unroll
        for (int i = 0; i < 4; ++i) {
          const int grow = wr * 32 + mi * 16 + quad * 4 + i;
          if (grow < XROW)
            atomicAdd(&G48[(size_t)grow * 64 + gcol], acc[mi][ni][i]);
        }
      }
    }
  } else {
    // XvT build: 16 blocks; lane<->n coalesced plane reads.
    const int n  = (bid - GSPL) * 64 + (tid & 63);
    const int kg = tid >> 6;
    const float* Xv4 = Xp + (size_t)8 * PLSZ;    // planes 8..11
#pragma unroll
    for (int s = 0; s < 4; ++s) {
      const int k0 = kg * 4 + s * 16;
      ushort4 o;
      unsigned short* oc = &o.x;
#pragma unroll
      for (int i = 0; i < 4; ++i) {
        const int k = k0 + i;
        float v = 0.f;
        if (k < 47) {
          const size_t off = (size_t)k * DIM + n;
          v = Xv4[off] + Xv4[off + PLSZ] + Xv4[off + 2 * PLSZ] +
              Xv4[off + 3 * PLSZ];
        }
        oc[i] = f2b(v);
      }
      *reinterpret_cast<ushort4*>(XvT + (size_t)n * 64 + k0) = o;
    }
  }
}

// ---------------------------------------------------------------------------
// K3: fused coefficients + output GEMM. Grid (256, 4): block = 16 moves x
// 256 cols. Phase A (proven coef_k body): stage G48 into padded LDS, token
// gather, in-lane softmax (lane L = row l of move g=tid>>4), column weights
// scattered into CL, hi/lo bf16 split -> LDS. Phase B: each wave does a
// 16x64 out tile: A-frags from LDS (16 moves x 64 k), B from XvT, 16 MFMA.
// out = C·XvT + 30*bv. Coef work is 4x redundant across blockIdx.y (cheap).
// ---------------------------------------------------------------------------
__global__ __launch_bounds__(256) void attn_gemm(
    const void* __restrict__ tokens_raw, const float* __restrict__ G48,
    const unsigned short* __restrict__ XvT, const float* __restrict__ bv,
    float* __restrict__ out) {
  __shared__ float Gs[XROW * 65];       // padded LD=65: gather conflict-free
  __shared__ float Sm[16][LW][17];
  __shared__ float CL[16][64];
  __shared__ __attribute__((aligned(16))) unsigned short CLh[16 * 72];
  __shared__ __attribute__((aligned(16))) unsigned short CLl[16 * 72];
  __shared__ int   tokL[16][16];
  __shared__ int   is64_s;
  const int m0  = blockIdx.x * 16;
  const int cb0 = blockIdx.y * 256;
  const int tid = threadIdx.x;

  const unsigned int* u32 = (const unsigned int*)tokens_raw;
  if (tid < 64) {  // int64 tokens (<32) have all odd 32-bit words zero
    unsigned int v = u32[2 * tid + 1];
    unsigned long long nz = __ballot(v != 0);
    if (tid == 0) is64_s = (nz == 0ULL) ? 1 : 0;
  }
#pragma unroll
  for (int i = 0; i < 12; ++i) {        // stage 48x64 G into padded LDS
    const int idx = i * 256 + tid;
    Gs[(idx >> 6) * 65 + (idx & 63)] = G48[idx];
  }
  {
    const int g = tid >> 4, L = tid & 15;
#pragma unroll
    for (int i = 0; i < 4; ++i) CL[g][L * 4 + i] = 0.f;
  }
  __syncthreads();  // is64_s + Gs + CL visible

  if (tid < 16 * LW) {
    const int mv = tid / LW, j = tid - mv * LW;
    int t;
    if (is64_s) t = (int)((const long long*)tokens_raw)[(size_t)(m0 + mv) * LW + j];
    else        t = ((const int*)tokens_raw)[(size_t)(m0 + mv) * LW + j];
    tokL[mv][j] = t;
  }
  __syncthreads();

  const int g = tid >> 4;
  const int L = tid & 15;
  if (L < LW) {  // lane L = row l of move (m0+g)
    const int rb0 = tokL[g][L] * 65;
    const int rb1 = (32 + L) * 65;
    const int rb2 = (XROW - 1) * 65;
    float S[LW];
#pragma unroll
    for (int j = 0; j < LW; ++j) {
      const int c0 = tokL[g][j];
      const int c1 = 32 + j;
      S[j] = Gs[rb0 + c0] + Gs[rb1 + c0] + Gs[rb2 + c0]
           + Gs[rb0 + c1] + Gs[rb1 + c1] + Gs[rb2 + c1];
    }
    float mx = S[0];
#pragma unroll
    for (int j = 1; j < LW; ++j) mx = fmaxf(mx, S[j]);
    float sum = 0.f;
#pragma unroll
    for (int j = 0; j < LW; ++j) { S[j] = __expf(S[j] - mx); sum += S[j]; }
    const float inv = 1.0f / sum;
#pragma unroll
    for (int j = 0; j < LW; ++j) Sm[g][L][j] = S[j] * inv;
  }
  __syncthreads();

  if (L < LW) {  // lane L = column j: w_j = 2 * sum_l P[l][j], scatter
    float s = 0.f;
#pragma unroll
    for (int l = 0; l < LW; ++l) s += Sm[g][l][L];
    const float wj = 2.0f * s;
    atomicAdd(&CL[g][tokL[g][L]], wj);  // token slots may collide
    CL[g][32 + L] = wj;                 // position slots unique
  }
  __syncthreads();

  {  // hi/lo bf16 split into LDS (rows g, padded stride 72)
    float4 cv = *reinterpret_cast<const float4*>(&CL[g][L * 4]);
    ushort4 hi, lo;
    hi.x = f2b(cv.x); hi.y = f2b(cv.y); hi.z = f2b(cv.z); hi.w = f2b(cv.w);
    lo.x = f2b(cv.x - b2f(hi.x)); lo.y = f2b(cv.y - b2f(hi.y));
    lo.z = f2b(cv.z - b2f(hi.z)); lo.w = f2b(cv.w - b2f(hi.w));
    *reinterpret_cast<ushort4*>(CLh + g * 72 + L * 4) = hi;
    *reinterpret_cast<ushort4*>(CLl + g * 72 + L * 4) = lo;
  }
  __syncthreads();

  // Phase B: wave w covers cols cb0 + w*64 .. +63 of all 16 moves.
  const int lane = tid & 63;
  const int wave = tid >> 6;
  const int quad = lane >> 4;
  const int l16  = lane & 15;
  const int colb = cb0 + wave * 64;

  floatx4 acc[4];
#pragma unroll
  for (int i = 0; i < 4; ++i) acc[i] = (floatx4){0.f, 0.f, 0.f, 0.f};

#pragma unroll
  for (int ks = 0; ks < 64; ks += 32) {
    short8 ah = *reinterpret_cast<const short8*>(CLh + l16 * 72 + ks + quad * 8);
    short8 al = *reinterpret_cast<const short8*>(CLl + l16 * 72 + ks + quad * 8);
#pragma unroll
    for (int ni = 0; ni < 4; ++ni) {
      const unsigned short* B = XvT + (size_t)(colb + ni * 16 + l16) * 64;
      short8 b = *reinterpret_cast<const short8*>(B + ks + quad * 8);
      acc[ni] = __builtin_amdgcn_mfma_f32_16x16x32_bf16(ah, b, acc[ni], 0, 0, 0);
      acc[ni] = __builtin_amdgcn_mfma_f32_16x16x32_bf16(al, b, acc[ni], 0, 0, 0);
    }
  }

#pragma unroll
  for (int ni = 0; ni < 4; ++ni) {
    const int gcol = colb + ni * 16 + l16;
    const float bias30 = 30.0f * bv[gcol];
#pragma unroll
    for (int i = 0; i < 4; ++i) {
      out[(size_t)(m0 + quad * 4 + i) * DIM + gcol] = acc[ni][i] + bias30;
    }
  }
}

// ---------------------------------------------------------------------------
extern "C" void kernel_launch(void* const* d_in, const int* in_sizes, int n_in,
                              void* d_out, int out_size, void* d_ws, size_t ws_size,
                              hipStream_t stream) {
  const void*  tokens = d_in[0];
  const float* letter = (const float*)d_in[1];
  const float* pos    = (const float*)d_in[2];
  const float* Wq     = (const float*)d_in[3];
  const float* bq     = (const float*)d_in[4];
  const float* Wk     = (const float*)d_in[5];
  const float* bk     = (const float*)d_in[6];
  const float* Wv     = (const float*)d_in[7];
  const float* bv     = (const float*)d_in[8];
  float*       outp   = (float*)d_out;   // reference output dtype = float32

  char* ws = (char*)d_ws;
  const size_t XP_SZ  = (size_t)12 * PLSZ * 4;      // 12 planes  = 2.25 MB
  const size_t G_SZ   = (size_t)XROW * 64 * 4;      // 12 KB
  float*          Xp  = (float*)(ws);
  float*          Gp  = (float*)(ws + XP_SZ);
  unsigned short* XvT = (unsigned short*)(ws + XP_SZ + G_SZ);

  proj_ksplit<<<dim3(KSPL, 16, 3), 256, 0, stream>>>(letter, pos, Wq, Wk, Wv,
                                                     Xp, Gp);
  gram_vexp<<<GSPL + 16, 256, 0, stream>>>(Xp, bq, bk, Gp, XvT);
  attn_gemm<<<dim3(NMOVES / 16, 4), 256, 0, stream>>>(tokens, Gp, XvT, bv, outp);
}